// Round 9
// baseline (75.875 us; speedup 1.0000x reference)
//
#include <hip/hip_runtime.h>
#include <stdint.h>

#define T_TRIALS 1000
#define B_SIZE   8192
#define P_SIZE   1024
#define CHUNK    32
#define KCH      32            // 31 full chunks + 8-step tail
#define NM       31            // maps 0..30 feed the scan
#define NWORDS   125           // T/8 packed u32 words per b
#define ER_DECAY 0.999f
#define LN_ER_DECAY (-1.0005003335835335e-3f)
#define LOG2E_F 1.4426950408889634f
#define LN2_F   0.69314718055994531f

typedef float f32x4_t __attribute__((ext_vector_type(4)));

__device__ __forceinline__ float sp_(float x){ return __logf(1.0f + __expf(x)); }   // softplus
__device__ __forceinline__ float sg_(float x){ return 1.0f / (1.0f + __expf(-x)); } // sigmoid
__device__ __forceinline__ float clampf(float x, float lo, float hi){ return fminf(fmaxf(x, lo), hi); }

// ===========================================================================
// Kernel 1: per-chunk affine map composition + 4-bit (choice,reward) packing
// (unchanged from round 8)
// ===========================================================================
__global__ __launch_bounds__(256)
void castro_chunkmap(const float* __restrict__ params,
                     const float* __restrict__ rewards,
                     const int*   __restrict__ choices,
                     const int*   __restrict__ pids,
                     float4*      __restrict__ stageA,   // [6][NM*B]
                     uint32_t*    __restrict__ packed)   // [NWORDS*B]
{
    const int b  = blockIdx.x * 256 + threadIdx.x;
    const int k  = blockIdx.y;
    const int t0 = k * CHUNK;

    const int*   cp = choices + (size_t)t0 * B_SIZE + b;
    const float* rp = rewards + (size_t)t0 * B_SIZE + b;
    uint32_t*    pk = packed + (size_t)(k * 4) * B_SIZE + b;

    if (k == NM) {   // tail chunk [992,1000): pack only (1 word)
        uint32_t gw = 0;
        #pragma unroll
        for (int i = 0; i < 8; ++i) {
            const int   c = cp[(size_t)i * B_SIZE];
            const float r = rp[(size_t)i * B_SIZE];
            gw |= ((uint32_t)c | (r > 0.5f ? 4u : 0u)) << (4*i);
        }
        pk[0] = gw;
        return;
    }

    const int pid = pids[b];
    const float p3  = clampf(params[ 3 * P_SIZE + pid], -5.0f, 5.0f);
    const float p4  = clampf(params[ 4 * P_SIZE + pid], -5.0f, 5.0f);
    const float p10 = clampf(params[10 * P_SIZE + pid], -5.0f, 5.0f);
    const float alpha_er = clampf(sg_(p3), 0.01f, 0.99f);
    const float decay    = clampf(sg_(p4), 0.01f, 0.99f);
    const float gam      = sp_(p10);
    const float gp1      = 1.0f + gam;

    float er = alpha_er * __expf((float)t0 * LN_ER_DECAY);

    float m00=1.f,m01=0.f,m02=0.f,m03=0.f;
    float m10=0.f,m11=1.f,m12=0.f,m13=0.f;
    float m20=0.f,m21=0.f,m22=1.f,m23=0.f;
    float m30=0.f,m31=0.f,m32=0.f,m33=1.f;
    float b0=0.f,b1=0.f,b2=0.f,b3=0.f;
    int   c0=0,c1=0,c2=0,c3=0;
    int   run=0, last=-1;

    #pragma unroll
    for (int g = 0; g < 4; ++g) {
        int cc[8]; float rr[8];
        #pragma unroll
        for (int i = 0; i < 8; ++i) {
            cc[i] = cp[(size_t)(g*8 + i) * B_SIZE];
            rr[i] = rp[(size_t)(g*8 + i) * B_SIZE];
        }
        uint32_t gw = 0;
        #pragma unroll
        for (int i = 0; i < 8; ++i) {
            const int   c = cc[i];
            const float r = rr[i];
            gw |= ((uint32_t)c | (r > 0.5f ? 4u : 0u)) << (4*i);

            er *= ER_DECAY;
            const float target = fmaf(r, gp1, -gam);
            const bool e0=(c==0), e1=(c==1), e2=(c==2), e3=(c==3);

            m00=e0?0.f:m00; m01=e0?0.f:m01; m02=e0?0.f:m02; m03=e0?0.f:m03; b0=e0?target:b0;
            m10=e1?0.f:m10; m11=e1?0.f:m11; m12=e1?0.f:m12; m13=e1?0.f:m13; b1=e1?target:b1;
            m20=e2?0.f:m20; m21=e2?0.f:m21; m22=e2?0.f:m22; m23=e2?0.f:m23; b2=e2?target:b2;
            m30=e3?0.f:m30; m31=e3?0.f:m31; m32=e3?0.f:m32; m33=e3?0.f:m33; b3=e3?target:b3;

            const float s0=(m00+m10)+(m20+m30);
            const float s1=(m01+m11)+(m21+m31);
            const float s2=(m02+m12)+(m22+m32);
            const float s3=(m03+m13)+(m23+m33);
            const float sb=(b0+b1)+(b2+b3);
            const float a  = decay * (1.0f - er);
            const float e4 = decay * er * 0.25f;

            m00=fmaf(e4,s0,a*m00); m01=fmaf(e4,s1,a*m01); m02=fmaf(e4,s2,a*m02); m03=fmaf(e4,s3,a*m03);
            m10=fmaf(e4,s0,a*m10); m11=fmaf(e4,s1,a*m11); m12=fmaf(e4,s2,a*m12); m13=fmaf(e4,s3,a*m13);
            m20=fmaf(e4,s0,a*m20); m21=fmaf(e4,s1,a*m21); m22=fmaf(e4,s2,a*m22); m23=fmaf(e4,s3,a*m23);
            m30=fmaf(e4,s0,a*m30); m31=fmaf(e4,s1,a*m31); m32=fmaf(e4,s2,a*m32); m33=fmaf(e4,s3,a*m33);
            b0=fmaf(e4,sb,a*b0); b1=fmaf(e4,sb,a*b1); b2=fmaf(e4,sb,a*b2); b3=fmaf(e4,sb,a*b3);

            c0 += e0; c1 += e1; c2 += e2; c3 += e3;
            run = (c == last) ? run + 1 : 1;
            last = c;
        }
        pk[(size_t)g * B_SIZE] = gw;
    }

    const size_t idx    = (size_t)k * B_SIZE + b;
    const size_t stride = (size_t)NM * B_SIZE;
    stageA[0*stride+idx] = make_float4(m00,m01,m02,m03);
    stageA[1*stride+idx] = make_float4(m10,m11,m12,m13);
    stageA[2*stride+idx] = make_float4(m20,m21,m22,m23);
    stageA[3*stride+idx] = make_float4(m30,m31,m32,m33);
    stageA[4*stride+idx] = make_float4(b0,b1,b2,b3);
    const int meta0 = c0 | (c1<<8) | (c2<<16) | (c3<<24);
    const int meta1 = last | (run<<8);
    stageA[5*stride+idx] = make_float4(__int_as_float(meta0), __int_as_float(meta1), 0.f, 0.f);
}

// ===========================================================================
// Kernel 2: wave-parallel combine with LDS-staged transpose.
// Block = 256 threads = 8 b (bi = tid>>5) x 32 scan lanes (k = tid&31).
// Load: coalesced b-minor global reads -> LDS (padded rows).
// Scan: Hillis-Steele over k via __shfl_up (width 32).
// Store: results staged to LDS, written out coalesced b-minor.
// ===========================================================================
__global__ __launch_bounds__(256)
void castro_combine_x(const float* __restrict__ params,
                      const int*   __restrict__ pids,
                      const float4* __restrict__ stageA,
                      float4*      __restrict__ cpsA,
                      float4*      __restrict__ cpsB)
{
    __shared__ float4 ldsm[NM * 49 + 8];   // 49 float4 per k-row (48 + 1 pad)
    __shared__ float4 ldsoA[NM * 8];
    __shared__ float4 ldsoB[NM * 8];

    const int tid = threadIdx.x;
    const int b0  = blockIdx.x * 8;

    // ---- coalesced load: stageA[plane][k*B + b0+bi] -> ldsm[49k + 8*plane + bi]
    for (int e = tid; e < NM * 48; e += 256) {
        const int k     = e / 48;
        const int r     = e - k * 48;          // plane*8 + bi
        const int plane = r >> 3;
        const int bi    = r & 7;
        ldsm[e + k] = stageA[(size_t)plane * NM * B_SIZE + (size_t)k * B_SIZE + b0 + bi];
    }
    __syncthreads();

    const int k  = tid & 31;
    const int bi = tid >> 5;
    const int b  = b0 + bi;

    const int pid = pids[b];
    const float p2 = clampf(params[2 * P_SIZE + pid], -5.0f, 5.0f);
    const float p3 = clampf(params[3 * P_SIZE + pid], -5.0f, 5.0f);
    const float prior    = clampf(sp_(p2), 0.01f, 0.99f);
    const float alpha_er = clampf(sg_(p3), 0.01f, 0.99f);

    float M[16], bv[4];
    int   cn[4], run, last, len;

    if (k < NM) {
        const int base = 49 * k + bi;
        const float4 r0 = ldsm[base];
        const float4 r1 = ldsm[base + 8];
        const float4 r2 = ldsm[base + 16];
        const float4 r3 = ldsm[base + 24];
        const float4 r4 = ldsm[base + 32];
        const float4 r5 = ldsm[base + 40];
        M[0]=r0.x; M[1]=r0.y; M[2]=r0.z;  M[3]=r0.w;
        M[4]=r1.x; M[5]=r1.y; M[6]=r1.z;  M[7]=r1.w;
        M[8]=r2.x; M[9]=r2.y; M[10]=r2.z; M[11]=r2.w;
        M[12]=r3.x; M[13]=r3.y; M[14]=r3.z; M[15]=r3.w;
        bv[0]=r4.x; bv[1]=r4.y; bv[2]=r4.z; bv[3]=r4.w;
        const int meta0 = __float_as_int(r5.x);
        const int meta1 = __float_as_int(r5.y);
        cn[0] =  meta0        & 255;
        cn[1] = (meta0 >> 8 ) & 255;
        cn[2] = (meta0 >> 16) & 255;
        cn[3] = (meta0 >> 24) & 255;
        last = meta1 & 255;
        run  = meta1 >> 8;
        len  = CHUNK;
    } else {                                        // lane 31: identity
        #pragma unroll
        for (int i = 0; i < 16; ++i) M[i] = (i % 5 == 0) ? 1.0f : 0.0f;
        bv[0]=bv[1]=bv[2]=bv[3]=0.f;
        cn[0]=cn[1]=cn[2]=cn[3]=0;
        run=0; last=-1; len=0;
    }

    // Hillis-Steele inclusive scan (offsets 1,2,4,8,16), width-32.
    #pragma unroll
    for (int o = 1; o < 32; o <<= 1) {
        float xM[16], xb[4];
        int   xc[4], xrun, xlast, xlen;
        #pragma unroll
        for (int i = 0; i < 16; ++i) xM[i] = __shfl_up(M[i], (unsigned)o, 32);
        #pragma unroll
        for (int i = 0; i < 4; ++i)  xb[i] = __shfl_up(bv[i], (unsigned)o, 32);
        #pragma unroll
        for (int i = 0; i < 4; ++i)  xc[i] = __shfl_up(cn[i], (unsigned)o, 32);
        xrun  = __shfl_up(run,  (unsigned)o, 32);
        xlast = __shfl_up(last, (unsigned)o, 32);
        xlen  = __shfl_up(len,  (unsigned)o, 32);

        const bool v = (k >= o);                    // lanes < o: X = identity
        #pragma unroll
        for (int i = 0; i < 16; ++i) xM[i] = v ? xM[i] : ((i % 5 == 0) ? 1.0f : 0.0f);
        #pragma unroll
        for (int i = 0; i < 4; ++i)  xb[i] = v ? xb[i] : 0.0f;
        #pragma unroll
        for (int i = 0; i < 4; ++i)  xc[i] = v ? xc[i] : 0;
        xrun  = v ? xrun  : 0;
        xlast = v ? xlast : -1;
        xlen  = v ? xlen  : 0;

        // compose: result = (segment X) then (segment Y=current)
        float nM[16], nb[4];
        #pragma unroll
        for (int r = 0; r < 4; ++r) {
            #pragma unroll
            for (int c = 0; c < 4; ++c) {
                nM[r*4+c] = fmaf(M[r*4+0], xM[0*4+c],
                             fmaf(M[r*4+1], xM[1*4+c],
                              fmaf(M[r*4+2], xM[2*4+c],
                                   M[r*4+3]* xM[3*4+c])));
            }
            nb[r] = fmaf(M[r*4+0], xb[0],
                     fmaf(M[r*4+1], xb[1],
                      fmaf(M[r*4+2], xb[2],
                       fmaf(M[r*4+3], xb[3], bv[r]))));
        }
        #pragma unroll
        for (int i = 0; i < 16; ++i) M[i] = nM[i];
        #pragma unroll
        for (int i = 0; i < 4; ++i)  bv[i] = nb[i];
        #pragma unroll
        for (int i = 0; i < 4; ++i)  cn[i] += xc[i];

        run = (run == len && last == xlast) ? xrun + run : run;
        len += xlen;
    }

    if (k < NM) {
        // q0 = prior * ones  ->  q_cp[r] = prior * rowsum(M[r]) + b[r]
        const float q0 = fmaf(prior, (M[0] +M[1]) +(M[2] +M[3]),  bv[0]);
        const float q1 = fmaf(prior, (M[4] +M[5]) +(M[6] +M[7]),  bv[1]);
        const float q2 = fmaf(prior, (M[8] +M[9]) +(M[10]+M[11]), bv[2]);
        const float q3 = fmaf(prior, (M[12]+M[13])+(M[14]+M[15]), bv[3]);

        const float er_b = alpha_er * __expf((float)((k+1)*CHUNK) * LN_ER_DECAY);
        const int   tsls = run - 1;

        ldsoA[(k<<3) + bi] = make_float4(q0, q1, q2, q3);
        ldsoB[(k<<3) + bi] = make_float4(er_b,
                                         __int_as_float(cn[0] | (cn[1]<<16)),
                                         __int_as_float(cn[2] | (cn[3]<<16)),
                                         __int_as_float((tsls & 0xFFFF) | (last<<16)));
    }
    __syncthreads();

    // ---- coalesced writeout: ldso[k*8+bi] -> cps[k*B + b0+bi]
    for (int e = tid; e < NM * 8; e += 256) {
        const int kk  = e >> 3;
        const int bb  = e & 7;
        const size_t ci = (size_t)kk * B_SIZE + b0 + bb;
        cpsA[ci] = ldsoA[e];
        cpsB[ci] = ldsoB[e];
    }
}

// ===========================================================================
// Kernel 3: per-chunk logit replay from packed stream (unchanged from round 8)
// ===========================================================================
__global__ __launch_bounds__(256)
void castro_emit(const float* __restrict__ params,
                 const int*   __restrict__ pids,
                 const float4* __restrict__ cpsA,
                 const float4* __restrict__ cpsB,
                 const uint32_t* __restrict__ packed,
                 float4*      __restrict__ out4)
{
    const int b  = blockIdx.x * 256 + threadIdx.x;
    const int k  = blockIdx.y;
    const int t0 = k * CHUNK;
    const int ngroups = (k == KCH-1) ? 1 : 4;
    const int pid = pids[b];

    float p[13];
    #pragma unroll
    for (int kk = 0; kk < 13; ++kk)
        p[kk] = clampf(params[kk * P_SIZE + pid], -5.0f, 5.0f);

    const float beta_r   = clampf(sp_(p[0]), 0.01f, 20.0f);
    const float lapse    = clampf(sg_(p[1]), 0.01f, 0.99f);
    const float prior    = clampf(sp_(p[2]), 0.01f, 0.99f);
    const float alpha_er = clampf(sg_(p[3]), 0.01f, 0.99f);
    const float decay    = clampf(sg_(p[4]), 0.01f, 0.99f);
    const float ab1      = p[5];
    const float ab2      = p[6];
    const float perv     = sp_(p[7]);
    const float sw       = p[8];
    const float gam      = sp_(p[10]);
    const float temp     = clampf(sp_(p[11]) + 1e-6f, 1e-6f, 100.0f);
    const float beta_p   = sp_(p[12]);

    const float bt2 = (beta_r / temp) * LOG2E_F;
    const float ol  = 1.0f - lapse;
    const float la4 = 0.25f * lapse;
    const float gp1 = 1.0f + gam;

    float q0,q1,q2,q3, er, ft;
    float f0,f1,f2,f3;
    int   old_c;
    if (k == 0) {
        q0=q1=q2=q3=prior; f0=f1=f2=f3=0.f; ft=0.f; old_c=-1; er=alpha_er;
    } else {
        const size_t ci = (size_t)(k-1) * B_SIZE + b;
        const float4 s0 = cpsA[ci];
        const float4 s1 = cpsB[ci];
        q0=s0.x; q1=s0.y; q2=s0.z; q3=s0.w;
        er = s1.x;
        const int u1=__float_as_int(s1.y), u2=__float_as_int(s1.z), u3=__float_as_int(s1.w);
        f0=(float)(u1&0xFFFF); f1=(float)(u1>>16);
        f2=(float)(u2&0xFFFF); f3=(float)(u2>>16);
        ft=(float)(u3&0xFFFF); old_c=(u3>>16);
    }

    float bpl0 = beta_p * __log2f(1.0f + f0);
    float bpl1 = beta_p * __log2f(1.0f + f1);
    float bpl2 = beta_p * __log2f(1.0f + f2);
    float bpl3 = beta_p * __log2f(1.0f + f3);

    const uint32_t* pk = packed + (size_t)(k * 4) * B_SIZE + b;
    float4* op = out4 + (size_t)t0 * B_SIZE + b;

    #pragma unroll
    for (int g = 0; g < 4; ++g) {
        if (g < ngroups) {
            uint32_t word = pk[(size_t)g * B_SIZE];
            #pragma unroll
            for (int i = 0; i < 8; ++i) {
                const int   code = (int)(word & 0xFu); word >>= 4;
                const int   c    = code & 3;
                const float r    = (float)((code >> 2) & 1);

                const float target = fmaf(r, gp1, -gam);
                const bool e0=(c==0), e1=(c==1), e2=(c==2), e3=(c==3);
                q0 = e0 ? target : q0;
                q1 = e1 ? target : q1;
                q2 = e2 ? target : q2;
                q3 = e3 ? target : q3;

                const bool same = (c == old_c);
                ft = same ? ft + 1.0f : 0.0f;
                er *= ER_DECAY;

                const float fsel = e0 ? f0 : (e1 ? f1 : (e2 ? f2 : f3));
                const float bplc = beta_p * __log2f(fsel + 2.0f);
                f0 += e0 ? 1.0f : 0.0f;
                f1 += e1 ? 1.0f : 0.0f;
                f2 += e2 ? 1.0f : 0.0f;
                f3 += e3 ? 1.0f : 0.0f;
                bpl0 = e0 ? bplc : bpl0;
                bpl1 = e1 ? bplc : bpl1;
                bpl2 = e2 ? bplc : bpl2;
                bpl3 = e3 ? bplc : bpl3;

                const float qm = 0.25f * ((q0+q1)+(q2+q3));
                q0 = decay * fmaf(er, qm - q0, q0);
                q1 = decay * fmaf(er, qm - q1, q1);
                q2 = decay * fmaf(er, qm - q2, q2);
                q3 = decay * fmaf(er, qm - q3, q3);

                const float s0 = fmaf(bt2, q0, bpl0);
                const float s1 = fmaf(bt2, q1, bpl1);
                const float s2 = fmaf(bt2, q2, bpl2);
                const float s3 = fmaf(bt2, q3, bpl3);

                const float m  = fmaxf(fmaxf(s0, s1), fmaxf(s2, s3));
                const float x0 = exp2f(s0 - m);
                const float x1 = exp2f(s1 - m);
                const float x2 = exp2f(s2 - m);
                const float x3 = exp2f(s3 - m);
                const float inv = __builtin_amdgcn_rcpf((x0+x1)+(x2+x3));
                const float sc  = ol * inv;

                const float L0 = __log2f(fmaf(sc, x0, la4));
                const float L1 = __log2f(fmaf(sc, x1, la4));
                const float L2 = __log2f(fmaf(sc, x2, la4));
                const float L3 = __log2f(fmaf(sc, x3, la4));

                const float bonus = fmaf(LN2_F, __log2f(ft + 1.0f), same ? perv : sw);

                float a0 = (e0 ? bonus : 0.0f) + ((old_c == 0) ? ab1 : 0.0f);
                float a1 = (e1 ? bonus : 0.0f) + ((old_c == 1) ? ab1 : 0.0f);
                float a2 = (e2 ? bonus : 0.0f) + ((old_c == 2) ? ab1 : 0.0f);
                float a3 = (e3 ? bonus : 0.0f) + ((old_c == 3) ? ab1 : 0.0f);
                const int c2 = (c + 2) & 3;
                a0 += (c2 == 0) ? ab2 : 0.0f;
                a1 += (c2 == 1) ? ab2 : 0.0f;
                a2 += (c2 == 2) ? ab2 : 0.0f;
                a3 += (c2 == 3) ? ab2 : 0.0f;

                f32x4_t v = { fmaf(LN2_F, L0, a0), fmaf(LN2_F, L1, a1),
                              fmaf(LN2_F, L2, a2), fmaf(LN2_F, L3, a3) };
                __builtin_nontemporal_store(v,
                    reinterpret_cast<f32x4_t*>(op + (size_t)(g*8 + i) * B_SIZE));
                old_c = c;
            }
        }
    }
}

// ===========================================================================
// FALLBACK: monolithic scan (only if workspace is too small).
// ===========================================================================
__global__ __launch_bounds__(64)
void castro_scan(const float* __restrict__ params,
                 const float* __restrict__ rewards,
                 const int*   __restrict__ choices,
                 const int*   __restrict__ pids,
                 float*       __restrict__ out)
{
    const int b = blockIdx.x * blockDim.x + threadIdx.x;
    if (b >= B_SIZE) return;
    const int pid = pids[b];
    float p[13];
    #pragma unroll
    for (int kk = 0; kk < 13; ++kk)
        p[kk] = clampf(params[kk * P_SIZE + pid], -5.0f, 5.0f);
    const float beta_r   = clampf(sp_(p[0]), 0.01f, 20.0f);
    const float lapse    = clampf(sg_(p[1]), 0.01f, 0.99f);
    const float prior    = clampf(sp_(p[2]), 0.01f, 0.99f);
    const float alpha_er = clampf(sg_(p[3]), 0.01f, 0.99f);
    const float decay    = clampf(sg_(p[4]), 0.01f, 0.99f);
    const float ab1 = p[5], ab2 = p[6];
    const float perv = sp_(p[7]), sw = p[8];
    const float gam  = sp_(p[10]);
    const float temp = clampf(sp_(p[11]) + 1e-6f, 1e-6f, 100.0f);
    const float beta_p = sp_(p[12]);
    const float bt = beta_r / temp, ol = 1.0f - lapse, la4 = 0.25f * lapse, gp1 = 1.0f + gam;

    float q0=prior,q1=prior,q2=prior,q3=prior;
    float n0=0,n1=0,n2=0,n3=0;
    int old_c=-1; float tsls=0.0f, er=alpha_er;
    const int* cp = choices + b;
    const float* rp = rewards + b;
    float4* op = reinterpret_cast<float4*>(out) + b;
    for (int t = 0; t < T_TRIALS; ++t) {
        const int c = cp[(size_t)t*B_SIZE];
        const float r = rp[(size_t)t*B_SIZE];
        const float target = fmaf(r, gp1, -gam);
        const bool e0=(c==0),e1=(c==1),e2=(c==2),e3=(c==3);
        q0=e0?target:q0; q1=e1?target:q1; q2=e2?target:q2; q3=e3?target:q3;
        const bool same = (c == old_c);
        tsls = same ? tsls + 1.0f : 0.0f;
        er *= ER_DECAY;
        n0+=e0?1.f:0.f; n1+=e1?1.f:0.f; n2+=e2?1.f:0.f; n3+=e3?1.f:0.f;
        const float qm = 0.25f*((q0+q1)+(q2+q3));
        q0 = decay*fmaf(er, qm-q0, q0); q1 = decay*fmaf(er, qm-q1, q1);
        q2 = decay*fmaf(er, qm-q2, q2); q3 = decay*fmaf(er, qm-q3, q3);
        float s0 = fmaf(bt,q0,beta_p*__logf(1.f+n0));
        float s1 = fmaf(bt,q1,beta_p*__logf(1.f+n1));
        float s2 = fmaf(bt,q2,beta_p*__logf(1.f+n2));
        float s3 = fmaf(bt,q3,beta_p*__logf(1.f+n3));
        const float m = fmaxf(fmaxf(s0,s1),fmaxf(s2,s3));
        const float x0=__expf(s0-m),x1=__expf(s1-m),x2=__expf(s2-m),x3=__expf(s3-m);
        const float inv=__builtin_amdgcn_rcpf((x0+x1)+(x2+x3));
        const float sc=ol*inv;
        float l0=__logf(fmaf(sc,x0,la4)), l1=__logf(fmaf(sc,x1,la4));
        float l2=__logf(fmaf(sc,x2,la4)), l3=__logf(fmaf(sc,x3,la4));
        const float bonus=(same?perv:sw)+__logf(tsls+1.0f);
        l0+=e0?bonus:0.f; l1+=e1?bonus:0.f; l2+=e2?bonus:0.f; l3+=e3?bonus:0.f;
        l0+=(old_c==0)?ab1:0.f; l1+=(old_c==1)?ab1:0.f; l2+=(old_c==2)?ab1:0.f; l3+=(old_c==3)?ab1:0.f;
        const int c2=(c+2)&3;
        l0+=(c2==0)?ab2:0.f; l1+=(c2==1)?ab2:0.f; l2+=(c2==2)?ab2:0.f; l3+=(c2==3)?ab2:0.f;
        op[(size_t)t*B_SIZE] = make_float4(l0,l1,l2,l3);
        old_c=c;
    }
}

extern "C" void kernel_launch(void* const* d_in, const int* in_sizes, int n_in,
                              void* d_out, int out_size, void* d_ws, size_t ws_size,
                              hipStream_t stream)
{
    const float* params  = (const float*)d_in[0];
    const float* rewards = (const float*)d_in[1];
    const int*   choices = (const int*)  d_in[2];
    const int*   pids    = (const int*)  d_in[3];

    // stageA: 6*NM*B float4 | cpsA,cpsB: NM*B float4 each | packed: NWORDS*B u32
    const size_t need = (size_t)NM * B_SIZE * 96
                      + (size_t)NM * B_SIZE * 32
                      + (size_t)NWORDS * B_SIZE * 4;

    if (ws_size >= need) {
        float4*   stageA = (float4*)d_ws;
        float4*   cpsA   = stageA + (size_t)6 * NM * B_SIZE;
        float4*   cpsB   = cpsA + (size_t)NM * B_SIZE;
        uint32_t* packed = (uint32_t*)(cpsB + (size_t)NM * B_SIZE);

        hipLaunchKernelGGL(castro_chunkmap, dim3(B_SIZE/256, KCH), dim3(256), 0, stream,
                           params, rewards, choices, pids, stageA, packed);
        hipLaunchKernelGGL(castro_combine_x, dim3(B_SIZE/8), dim3(256), 0, stream,
                           params, pids, stageA, cpsA, cpsB);
        hipLaunchKernelGGL(castro_emit, dim3(B_SIZE/256, KCH), dim3(256), 0, stream,
                           params, pids, cpsA, cpsB, packed, (float4*)d_out);
        return;
    }

    hipLaunchKernelGGL(castro_scan, dim3(B_SIZE/64), dim3(64), 0, stream,
                       params, rewards, choices, pids, (float*)d_out);
}

// Round 10
// 63.832 us; speedup vs baseline: 1.1887x; 1.1887x over previous
//
#include <hip/hip_runtime.h>
#include <stdint.h>

#define T_TRIALS 1000
#define B_SIZE   8192
#define P_SIZE   1024
#define CHUNK    32
#define KCH      32            // 31 full chunks + 8-step tail
#define NM       31            // maps 0..30 feed the scan
#define BPB      16            // batch elements per block
#define BP       17            // padded row (bank-conflict break)
#define ER_DECAY 0.999f
#define LN_ER_DECAY (-1.0005003335835335e-3f)
#define LOG2E_F 1.4426950408889634f
#define LN2_F   0.69314718055994531f

typedef float f32x4_t __attribute__((ext_vector_type(4)));

__device__ __forceinline__ float sp_(float x){ return __logf(1.0f + __expf(x)); }   // softplus
__device__ __forceinline__ float sg_(float x){ return 1.0f / (1.0f + __expf(-x)); } // sigmoid
__device__ __forceinline__ float clampf(float x, float lo, float hi){ return fminf(fmaxf(x, lo), hi); }

// ===========================================================================
// Single fused kernel, b-major lanes.
// Block = 512 threads = 32 chunks (k = tid>>4) x 16 b (bi = tid&15).
// Phase 1: each thread composes its chunk's affine q-map (-> LDS) and packs
//          its chunk's (choice,reward) stream into 4 VGPRs.
// Phase 2: threads 0..15 serially scan the 31 maps for their b -> LDS
//          checkpoints (state entering each chunk).
// Phase 3: every thread emits its chunk's logits from registers + checkpoint.
// All global accesses are b-contiguous (>=64B segments).
// ===========================================================================
__global__ __launch_bounds__(512)
void castro_fused2(const float* __restrict__ params,
                   const float* __restrict__ rewards,
                   const int*   __restrict__ choices,
                   const int*   __restrict__ pids,
                   float4*      __restrict__ out4)
{
    __shared__ float4 smap0[NM][BP];
    __shared__ float4 smap1[NM][BP];
    __shared__ float4 smap2[NM][BP];
    __shared__ float4 smap3[NM][BP];
    __shared__ float4 smap4[NM][BP];
    __shared__ float2 smeta[NM][BP];
    __shared__ float4 scpA[KCH][BPB];
    __shared__ float4 scpB[KCH][BPB];

    const int tid = threadIdx.x;
    const int k   = tid >> 4;
    const int bi  = tid & 15;
    const int b   = blockIdx.x * BPB + bi;
    const int t0  = k * CHUNK;
    const int pid = pids[b];

    float p[13];
    #pragma unroll
    for (int kk = 0; kk < 13; ++kk)
        p[kk] = clampf(params[kk * P_SIZE + pid], -5.0f, 5.0f);

    const float beta_r   = clampf(sp_(p[0]), 0.01f, 20.0f);
    const float lapse    = clampf(sg_(p[1]), 0.01f, 0.99f);
    const float prior    = clampf(sp_(p[2]), 0.01f, 0.99f);
    const float alpha_er = clampf(sg_(p[3]), 0.01f, 0.99f);
    const float decay    = clampf(sg_(p[4]), 0.01f, 0.99f);
    const float ab1      = p[5];
    const float ab2      = p[6];
    const float perv     = sp_(p[7]);
    const float sw       = p[8];
    const float gam      = sp_(p[10]);
    const float temp     = clampf(sp_(p[11]) + 1e-6f, 1e-6f, 100.0f);
    const float beta_p   = sp_(p[12]);

    const float bt2 = (beta_r / temp) * LOG2E_F;
    const float ol  = 1.0f - lapse;
    const float la4 = 0.25f * lapse;
    const float gp1 = 1.0f + gam;

    const int*   cp = choices + (size_t)t0 * B_SIZE + b;
    const float* rp = rewards + (size_t)t0 * B_SIZE + b;

    uint32_t wr[4] = {0u, 0u, 0u, 0u};

    // ---------------- phase 1: pack + per-chunk map composition ----------------
    if (k < NM) {
        float er = alpha_er * __expf((float)t0 * LN_ER_DECAY);

        float m00=1.f,m01=0.f,m02=0.f,m03=0.f;
        float m10=0.f,m11=1.f,m12=0.f,m13=0.f;
        float m20=0.f,m21=0.f,m22=1.f,m23=0.f;
        float m30=0.f,m31=0.f,m32=0.f,m33=1.f;
        float b0=0.f,b1=0.f,b2=0.f,b3=0.f;
        int   c0=0,c1=0,c2=0,c3=0;
        int   run=0, last=-1;

        #pragma unroll
        for (int g = 0; g < 4; ++g) {
            int cc[8]; float rr[8];
            #pragma unroll
            for (int i = 0; i < 8; ++i) {
                cc[i] = cp[(size_t)(g*8 + i) * B_SIZE];
                rr[i] = rp[(size_t)(g*8 + i) * B_SIZE];
            }
            uint32_t gw = 0;
            #pragma unroll
            for (int i = 0; i < 8; ++i) {
                const int   c = cc[i];
                const float r = rr[i];
                gw |= ((uint32_t)c | (r > 0.5f ? 4u : 0u)) << (4*i);

                er *= ER_DECAY;
                const float target = fmaf(r, gp1, -gam);
                const bool e0=(c==0), e1=(c==1), e2=(c==2), e3=(c==3);

                m00=e0?0.f:m00; m01=e0?0.f:m01; m02=e0?0.f:m02; m03=e0?0.f:m03; b0=e0?target:b0;
                m10=e1?0.f:m10; m11=e1?0.f:m11; m12=e1?0.f:m12; m13=e1?0.f:m13; b1=e1?target:b1;
                m20=e2?0.f:m20; m21=e2?0.f:m21; m22=e2?0.f:m22; m23=e2?0.f:m23; b2=e2?target:b2;
                m30=e3?0.f:m30; m31=e3?0.f:m31; m32=e3?0.f:m32; m33=e3?0.f:m33; b3=e3?target:b3;

                const float s0=(m00+m10)+(m20+m30);
                const float s1=(m01+m11)+(m21+m31);
                const float s2=(m02+m12)+(m22+m32);
                const float s3=(m03+m13)+(m23+m33);
                const float sb=(b0+b1)+(b2+b3);
                const float a  = decay * (1.0f - er);
                const float e4 = decay * er * 0.25f;

                m00=fmaf(e4,s0,a*m00); m01=fmaf(e4,s1,a*m01); m02=fmaf(e4,s2,a*m02); m03=fmaf(e4,s3,a*m03);
                m10=fmaf(e4,s0,a*m10); m11=fmaf(e4,s1,a*m11); m12=fmaf(e4,s2,a*m12); m13=fmaf(e4,s3,a*m13);
                m20=fmaf(e4,s0,a*m20); m21=fmaf(e4,s1,a*m21); m22=fmaf(e4,s2,a*m22); m23=fmaf(e4,s3,a*m23);
                m30=fmaf(e4,s0,a*m30); m31=fmaf(e4,s1,a*m31); m32=fmaf(e4,s2,a*m32); m33=fmaf(e4,s3,a*m33);
                b0=fmaf(e4,sb,a*b0); b1=fmaf(e4,sb,a*b1); b2=fmaf(e4,sb,a*b2); b3=fmaf(e4,sb,a*b3);

                c0 += e0; c1 += e1; c2 += e2; c3 += e3;
                run = (c == last) ? run + 1 : 1;
                last = c;
            }
            wr[g] = gw;
        }

        smap0[k][bi] = make_float4(m00,m01,m02,m03);
        smap1[k][bi] = make_float4(m10,m11,m12,m13);
        smap2[k][bi] = make_float4(m20,m21,m22,m23);
        smap3[k][bi] = make_float4(m30,m31,m32,m33);
        smap4[k][bi] = make_float4(b0,b1,b2,b3);
        const int meta0 = c0 | (c1<<8) | (c2<<16) | (c3<<24);
        const int meta1 = last | (run<<8);
        smeta[k][bi] = make_float2(__int_as_float(meta0), __int_as_float(meta1));
    } else {
        // tail chunk [992,1000): pack only (its map is never consumed)
        uint32_t gw = 0;
        #pragma unroll
        for (int i = 0; i < 8; ++i) {
            const int   c = cp[(size_t)i * B_SIZE];
            const float r = rp[(size_t)i * B_SIZE];
            gw |= ((uint32_t)c | (r > 0.5f ? 4u : 0u)) << (4*i);
        }
        wr[0] = gw;
    }

    __syncthreads();

    // ---------------- phase 2: serial scan (threads 0..15, one per b) ----------------
    if (tid < BPB) {
        float q0=prior, q1=prior, q2=prior, q3=prior;
        int n0=0,n1=0,n2=0,n3=0;
        int g_run=0, g_last=-1;

        for (int k2 = 0; k2 < KCH; ++k2) {
            const float er_k = alpha_er * __expf((float)(k2*CHUNK) * LN_ER_DECAY);
            const int   tsls = (g_run > 0) ? (g_run - 1) : 0;
            scpA[k2][tid] = make_float4(q0,q1,q2,q3);
            scpB[k2][tid] = make_float4(er_k,
                                        __int_as_float(n0 | (n1<<16)),
                                        __int_as_float(n2 | (n3<<16)),
                                        __int_as_float((tsls & 0xFFFF) | (g_last<<16)));
            if (k2 < NM) {
                const float4 r0 = smap0[k2][tid];
                const float4 r1 = smap1[k2][tid];
                const float4 r2 = smap2[k2][tid];
                const float4 r3 = smap3[k2][tid];
                const float4 r4 = smap4[k2][tid];
                const float2 r5 = smeta[k2][tid];
                const float nq0 = fmaf(r0.w,q3, fmaf(r0.z,q2, fmaf(r0.y,q1, fmaf(r0.x,q0, r4.x))));
                const float nq1 = fmaf(r1.w,q3, fmaf(r1.z,q2, fmaf(r1.y,q1, fmaf(r1.x,q0, r4.y))));
                const float nq2 = fmaf(r2.w,q3, fmaf(r2.z,q2, fmaf(r2.y,q1, fmaf(r2.x,q0, r4.z))));
                const float nq3 = fmaf(r3.w,q3, fmaf(r3.z,q2, fmaf(r3.y,q1, fmaf(r3.x,q0, r4.w))));
                q0=nq0; q1=nq1; q2=nq2; q3=nq3;

                const int meta0 = __float_as_int(r5.x);
                const int meta1 = __float_as_int(r5.y);
                n0 += ( meta0        & 255);
                n1 += ((meta0 >> 8 ) & 255);
                n2 += ((meta0 >> 16) & 255);
                n3 += ((meta0 >> 24) & 255);
                const int last = meta1 & 255;
                const int rn   = meta1 >> 8;
                g_run  = (rn == CHUNK && last == g_last) ? g_run + CHUNK : rn;
                g_last = last;
            }
        }
    }
    __syncthreads();

    // ---------------- phase 3: emit logits for own chunk ----------------
    {
        const float4 sA = scpA[k][bi];
        const float4 sB = scpB[k][bi];
        float q0=sA.x, q1=sA.y, q2=sA.z, q3=sA.w;
        float er = sB.x;
        const int u1 = __float_as_int(sB.y);
        const int u2 = __float_as_int(sB.z);
        const int u3 = __float_as_int(sB.w);
        float f0 = (float)(u1 & 0xFFFF), f1 = (float)(u1 >> 16);
        float f2 = (float)(u2 & 0xFFFF), f3 = (float)(u2 >> 16);
        float ft = (float)(u3 & 0xFFFF);
        int   old_c = u3 >> 16;            // arithmetic shift: -1 survives

        float bpl0 = beta_p * __log2f(1.0f + f0);
        float bpl1 = beta_p * __log2f(1.0f + f1);
        float bpl2 = beta_p * __log2f(1.0f + f2);
        float bpl3 = beta_p * __log2f(1.0f + f3);

        float4* op = out4 + (size_t)t0 * B_SIZE + b;
        const int ngroups = (k == KCH-1) ? 1 : 4;

        #pragma unroll
        for (int g = 0; g < 4; ++g) {
            if (g < ngroups) {
                uint32_t word = wr[g];
                #pragma unroll
                for (int i = 0; i < 8; ++i) {
                    const int   code = (int)(word & 0xFu); word >>= 4;
                    const int   c    = code & 3;
                    const float r    = (float)((code >> 2) & 1);

                    const float target = fmaf(r, gp1, -gam);
                    const bool e0=(c==0), e1=(c==1), e2=(c==2), e3=(c==3);
                    q0 = e0 ? target : q0;
                    q1 = e1 ? target : q1;
                    q2 = e2 ? target : q2;
                    q3 = e3 ? target : q3;

                    const bool same = (c == old_c);
                    ft = same ? ft + 1.0f : 0.0f;
                    er *= ER_DECAY;

                    const float fsel = e0 ? f0 : (e1 ? f1 : (e2 ? f2 : f3));
                    const float bplc = beta_p * __log2f(fsel + 2.0f);
                    f0 += e0 ? 1.0f : 0.0f;
                    f1 += e1 ? 1.0f : 0.0f;
                    f2 += e2 ? 1.0f : 0.0f;
                    f3 += e3 ? 1.0f : 0.0f;
                    bpl0 = e0 ? bplc : bpl0;
                    bpl1 = e1 ? bplc : bpl1;
                    bpl2 = e2 ? bplc : bpl2;
                    bpl3 = e3 ? bplc : bpl3;

                    const float qm = 0.25f * ((q0+q1)+(q2+q3));
                    q0 = decay * fmaf(er, qm - q0, q0);
                    q1 = decay * fmaf(er, qm - q1, q1);
                    q2 = decay * fmaf(er, qm - q2, q2);
                    q3 = decay * fmaf(er, qm - q3, q3);

                    const float s0 = fmaf(bt2, q0, bpl0);
                    const float s1 = fmaf(bt2, q1, bpl1);
                    const float s2 = fmaf(bt2, q2, bpl2);
                    const float s3 = fmaf(bt2, q3, bpl3);

                    const float m  = fmaxf(fmaxf(s0, s1), fmaxf(s2, s3));
                    const float x0 = exp2f(s0 - m);
                    const float x1 = exp2f(s1 - m);
                    const float x2 = exp2f(s2 - m);
                    const float x3 = exp2f(s3 - m);
                    const float inv = __builtin_amdgcn_rcpf((x0+x1)+(x2+x3));
                    const float sc  = ol * inv;

                    const float L0 = __log2f(fmaf(sc, x0, la4));
                    const float L1 = __log2f(fmaf(sc, x1, la4));
                    const float L2 = __log2f(fmaf(sc, x2, la4));
                    const float L3 = __log2f(fmaf(sc, x3, la4));

                    const float bonus = fmaf(LN2_F, __log2f(ft + 1.0f), same ? perv : sw);

                    float a0 = (e0 ? bonus : 0.0f) + ((old_c == 0) ? ab1 : 0.0f);
                    float a1 = (e1 ? bonus : 0.0f) + ((old_c == 1) ? ab1 : 0.0f);
                    float a2 = (e2 ? bonus : 0.0f) + ((old_c == 2) ? ab1 : 0.0f);
                    float a3 = (e3 ? bonus : 0.0f) + ((old_c == 3) ? ab1 : 0.0f);
                    const int c2 = (c + 2) & 3;
                    a0 += (c2 == 0) ? ab2 : 0.0f;
                    a1 += (c2 == 1) ? ab2 : 0.0f;
                    a2 += (c2 == 2) ? ab2 : 0.0f;
                    a3 += (c2 == 3) ? ab2 : 0.0f;

                    f32x4_t v = { fmaf(LN2_F, L0, a0), fmaf(LN2_F, L1, a1),
                                  fmaf(LN2_F, L2, a2), fmaf(LN2_F, L3, a3) };
                    __builtin_nontemporal_store(v,
                        reinterpret_cast<f32x4_t*>(op + (size_t)(g*8 + i) * B_SIZE));
                    old_c = c;
                }
            }
        }
    }
}

extern "C" void kernel_launch(void* const* d_in, const int* in_sizes, int n_in,
                              void* d_out, int out_size, void* d_ws, size_t ws_size,
                              hipStream_t stream)
{
    const float* params  = (const float*)d_in[0];
    const float* rewards = (const float*)d_in[1];
    const int*   choices = (const int*)  d_in[2];
    const int*   pids    = (const int*)  d_in[3];

    hipLaunchKernelGGL(castro_fused2, dim3(B_SIZE/BPB), dim3(512), 0, stream,
                       params, rewards, choices, pids, (float4*)d_out);
}